// Round 5
// baseline (264.182 us; speedup 1.0000x reference)
//
#include <hip/hip_runtime.h>
#include <cstdint>
#include <cstddef>

// LSTM cell: B=4096, IN=1024, H=1024
//   ifgo = h @ Wh^T + bh + x @ Wx^T    [4096 x 4096]
//   i,f,g,o = split(ifgo); c' = sig(f)*c + sig(i)*tanh(g); h' = o*tanh(c')
//
// Pipeline (2 dispatches):
//   1. convert: fp32->bf16, 8 floats/thread (16B stores), K=2048 layout
//      (A_cat=[h|x], W_cat=[Wh|Wx]) with W rows permuted
//      p=((j>>4)<<6)|(gate<<4)|(j&15).   (identical to round-2/4)
//   2. gemm: 128x128 tile, BK=64, 4 waves.  LDS-TRAFFIC-HALVED design:
//      A operand read directly from global (16KB k-panel is L1-resident,
//      2x wave reuse via L1 hits; acc[4][4] keeps regs ~164 -> no spill,
//      unlike r3's 256^2 attempt).  B staged in LDS via global_load_lds
//      (XOR swizzle, conflicts=0) with the r4-proven counted-vmcnt clump
//      (vmcnt(4), never 0).  LDS/block = 32KB -> ~3 blocks/CU for
//      cross-block pipe overlap.  Fused fast-math LSTM gate epilogue.

#define NB   4096
#define KH   1024
#define KK   2048
#define ARR_ELEMS 4194304  // 4096*1024
#define NKT  32            // K tiles of 64

typedef __bf16 bf16x8 __attribute__((ext_vector_type(8)));
typedef float  f32x4  __attribute__((ext_vector_type(4)));

__device__ inline unsigned short f2bf(float f) {
    union { float f; unsigned int u; } v; v.f = f;
    unsigned int u = v.u;
    u += 0x7FFFu + ((u >> 16) & 1u);   // RNE
    return (unsigned short)(u >> 16);
}

__device__ inline float fsig(float v)  { return __builtin_amdgcn_rcpf(1.f + __expf(-v)); }
__device__ inline float ftanh(float v) { return 1.f - 2.f * __builtin_amdgcn_rcpf(1.f + __expf(2.f * v)); }

// ---------------------------------------------------------------- convert ---
__global__ void convert_kernel(const float* __restrict__ h, const float* __restrict__ x,
                               const float* __restrict__ Wh, const float* __restrict__ Wx,
                               unsigned short* __restrict__ A, unsigned short* __restrict__ W) {
    int idx = blockIdx.x * 256 + threadIdx.x;       // 0 .. 2M-1
    int arr = idx >> 19;
    int off = (idx & 0x7FFFF) << 3;
    const float* src = (arr == 0) ? h : (arr == 1) ? x : (arr == 2) ? Wh : Wx;
    float4 v0 = *(const float4*)(src + off);
    float4 v1 = *(const float4*)(src + off + 4);
    uint4 packed;
    packed.x = (unsigned int)f2bf(v0.x) | ((unsigned int)f2bf(v0.y) << 16);
    packed.y = (unsigned int)f2bf(v0.z) | ((unsigned int)f2bf(v0.w) << 16);
    packed.z = (unsigned int)f2bf(v1.x) | ((unsigned int)f2bf(v1.y) << 16);
    packed.w = (unsigned int)f2bf(v1.z) | ((unsigned int)f2bf(v1.w) << 16);

    int row = off >> 10;
    int col = off & 1023;
    unsigned short* dst;
    size_t dstOff;
    if (arr < 2) {                                  // A_cat: [h | x] per row
        dst = A;
        dstOff = (size_t)row * KK + (arr == 1 ? 1024 : 0) + col;
    } else {                                        // W_cat: permuted rows
        int g = row >> 10, j = row & 1023;
        int p = ((j >> 4) << 6) | (g << 4) | (j & 15);
        dst = W;
        dstOff = (size_t)p * KK + (arr == 3 ? 1024 : 0) + col;
    }
    *(uint4*)(dst + dstOff) = packed;
}

// ------------------------------------------------------------------- gemm ---
// 256 threads = 4 waves (2M x 2N). Wave output 64x64 (acc[4][4]).
//
// Per K-tile T (buf = T&1):
//   A frags: 8x global_load_dwordx4 (L1-resident 16KB panel, no LDS)
//   B frags: 8x ds_read_b128 (swizzled LDS, conflicts=0)
//   32x MFMA 16x16x32  (compiler inserts counted lgkm/vm waits)
//   lgkm(0) ; barrier          <- all waves done reading Bs[buf]
//   STAGE_B(T+2 -> buf)        <- 4x global_load_lds, write-after-read safe
//   vmcnt(4) ; barrier         <- B stage of tile T+1 landed (A loads of T
//                                 completed earlier via MFMA operand waits)
__global__ __launch_bounds__(256, 2) void gemm_kernel(const unsigned short* __restrict__ A,
                            const unsigned short* __restrict__ W,
                            const float* __restrict__ bh,
                            const float* __restrict__ c,
                            float* __restrict__ out) {
    __shared__ __align__(16) unsigned short Bs[2 * 8192];   // 32 KiB (B only)

    const int tid  = threadIdx.x;
    const int wave = tid >> 6;
    const int lane = tid & 63;

    // T1: 1024 blocks, 8 XCDs -> 128 contiguous tile-ids per XCD
    const int bid   = (int)blockIdx.x;
    const int swz   = (bid & 7) * 128 + (bid >> 3);
    const int tileM = swz >> 5;        // 0..31
    const int tileN = swz & 31;        // 0..31

    const int mBase = (wave >> 1) * 64;
    const int nBase = (wave & 1) * 64;
    const int fr  = lane & 15;
    const int fkE = (lane >> 4) * 8;      // fragment k-offset elems {0,8,16,24}
    const int fk2 = fkE * 2;              // ... bytes

    // ---- A: direct global pointers, one per 16-row M-fragment -------------
    // Per instr: 16 rows x 64B contiguous-per-row; k-panel 16KB -> L1 hits,
    // shared by both wc-waves of the same wr half.
    const unsigned short* pA[4];
    #pragma unroll
    for (int i = 0; i < 4; ++i)
        pA[i] = A + (size_t)(tileM * 128 + mBase + i * 16 + fr) * KK + fkE;

    // ---- B staging: per-thread pre-swizzled global source pointers --------
    const unsigned short* pb[4];
    #pragma unroll
    for (int i = 0; i < 4; ++i) {
        const int P   = (i * 256 + tid) * 16;
        const int L   = P ^ (((P >> 7) & 7) << 4);
        const int row = L >> 7;            // 0..127
        const int kk  = (L & 127) >> 1;    // elem 0..63
        pb[i] = W + (size_t)(tileN * 128 + row) * KK + kk;
    }

    // ---- B compute-side swizzled LDS byte offsets -------------------------
    const int swzm = (fr & 7) << 4;
    int offB[4];
    #pragma unroll
    for (int i = 0; i < 4; ++i)
        offB[i] = (nBase + i * 16 + fr) * 128 + (fk2 ^ swzm);
    // second K=32 panel: offset ^ 64

    f32x4 acc[4][4] = {};

#define STAGE(KT, BUF) do { \
    const size_t _ko = (size_t)(KT) * 64; \
    _Pragma("unroll") \
    for (int _i = 0; _i < 4; ++_i) { \
        __builtin_amdgcn_global_load_lds( \
            (const __attribute__((address_space(1))) void*)(pb[_i] + _ko), \
            (__attribute__((address_space(3))) void*)(Bs + (BUF) * 8192 + _i * 2048 + wave * 512), 16, 0, 0); \
    } \
} while (0)

// Hazard invariants:
//  - Bs tile T confirmed landed by tile T-1's vmcnt(4)+barrier
//  - lgkm(0)+barrier after the b-reads -> Bs[buf] dead for every wave
//  - STAGE(T+2->buf) issued after that barrier (write-after-read safe)
//  - at the clump, this wave's VMEM queue = [stage(T+1):4 (old)] +
//    [A(T):8 (completed via MFMA operand waits)] + [stage(T+2):4 (new)];
//    vmcnt(4) confirms everything except the 4 new -> tile T+1's B landed
//  - A loads of T+1 cannot hoist above the clump ("memory" clobbers)
#define TILEBODY(T, BUF) do { \
    const char* BsB = (const char*)Bs + (BUF) * 16384; \
    bf16x8 a[4][2], b[4][2]; \
    _Pragma("unroll") \
    for (int i = 0; i < 4; ++i) { \
        a[i][0] = *(const bf16x8*)(pA[i] + (size_t)(T) * 64); \
        a[i][1] = *(const bf16x8*)(pA[i] + (size_t)(T) * 64 + 32); \
    } \
    _Pragma("unroll") \
    for (int i = 0; i < 4; ++i) { \
        b[i][0] = *(const bf16x8*)(BsB + offB[i]); \
        b[i][1] = *(const bf16x8*)(BsB + (offB[i] ^ 64)); \
    } \
    _Pragma("unroll") \
    for (int i = 0; i < 4; ++i) \
        _Pragma("unroll") \
        for (int j = 0; j < 4; ++j) \
            _Pragma("unroll") \
            for (int s = 0; s < 2; ++s) \
                acc[i][j] = __builtin_amdgcn_mfma_f32_16x16x32_bf16( \
                    a[i][s], b[j][s], acc[i][j], 0, 0, 0); \
    asm volatile("s_waitcnt lgkmcnt(0)" ::: "memory"); \
    asm volatile("s_barrier" ::: "memory"); \
    { \
        const int _kt = ((T) + 2 <= NKT - 1) ? ((T) + 2) : (NKT - 1); \
        STAGE(_kt, BUF);   /* tail-clamped: writes target only dead buffers */ \
    } \
    asm volatile("s_waitcnt vmcnt(4)" ::: "memory"); \
    asm volatile("s_barrier" ::: "memory"); \
} while (0)

    // prologue: B(0),B(1) in flight; wait until tile 0's 4 loads landed
    STAGE(0, 0);
    STAGE(1, 1);
    asm volatile("s_waitcnt vmcnt(4)" ::: "memory");
    asm volatile("s_barrier" ::: "memory");

    for (int tt = 0; tt < NKT; tt += 2) {
        TILEBODY(tt, 0);
        TILEBODY(tt + 1, 1);
    }
#undef TILEBODY
#undef STAGE

    // ---- fused LSTM gate epilogue (r0-verified 128^2 mapping) -------------
    // acc[i][g][r]: row = tileM*128 + mBase + i*16 + (lane>>4)*4 + r,
    // gate g, logical j = (tileN*2 + (wave&1))*16 + (lane&15)
    const int j = ((tileN * 2 + (wave & 1)) << 4) | fr;
    const float bi  = bh[j];
    const float bff = bh[j + 1024];
    const float bg  = bh[j + 2048];
    const float bo  = bh[j + 3072];

    const int row0 = tileM * 128 + mBase + (lane >> 4) * 4;

    float cv[4][4];
    #pragma unroll
    for (int i = 0; i < 4; ++i)
        #pragma unroll
        for (int r = 0; r < 4; ++r)
            cv[i][r] = c[(size_t)(row0 + i * 16 + r) * KH + j];

    #pragma unroll
    for (int i = 0; i < 4; ++i) {
        #pragma unroll
        for (int r = 0; r < 4; ++r) {
            const size_t idx = (size_t)(row0 + i * 16 + r) * KH + j;
            float iv = fsig(acc[i][0][r] + bi);
            float fv = fsig(acc[i][1][r] + bff);
            float gv = ftanh(acc[i][2][r] + bg);
            float ov = fsig(acc[i][3][r] + bo);
            float cn = fv * cv[i][r] + iv * gv;
            float hn = ov * ftanh(cn);
            out[idx] = hn;
            out[(size_t)ARR_ELEMS + idx] = cn;
        }
    }
}

// ----------------------------------------------------------------- launch ---
extern "C" void kernel_launch(void* const* d_in, const int* in_sizes, int n_in,
                              void* d_out, int out_size, void* d_ws, size_t ws_size,
                              hipStream_t stream) {
    const float* x  = (const float*)d_in[0];
    const float* h  = (const float*)d_in[1];
    const float* c  = (const float*)d_in[2];
    const float* Wh = (const float*)d_in[3];
    const float* bh = (const float*)d_in[4];
    const float* Wx = (const float*)d_in[5];
    float* out = (float*)d_out;

    unsigned short* ws   = (unsigned short*)d_ws;
    unsigned short* Acat = ws;
    unsigned short* Wcat = ws + 2 * (size_t)ARR_ELEMS;

    convert_kernel<<<8192, 256, 0, stream>>>(h, x, Wh, Wx, Acat, Wcat);
    dim3 grid(1024);
    gemm_kernel<<<grid, 256, 0, stream>>>(Acat, Wcat, bh, c, out);
}

// Round 6
// 188.817 us; speedup vs baseline: 1.3991x; 1.3991x over previous
//
#include <hip/hip_runtime.h>
#include <cstdint>
#include <cstddef>

// LSTM cell: B=4096, IN=1024, H=1024
//   ifgo = h @ Wh^T + bh + x @ Wx^T    [4096 x 4096]
//   i,f,g,o = split(ifgo); c' = sig(f)*c + sig(i)*tanh(g); h' = o*tanh(c')
//
// Pipeline (2 dispatches):
//   1. convert: fp32->bf16, 8 floats/thread, K=2048 layout (A_cat=[h|x],
//      W_cat=[Wh|Wx]) with W rows permuted p=((j>>4)<<6)|(gate<<4)|(j&15).
//   2. gemm: 256x256 tile, BK=64, 8 waves, faithful 8-phase-per-2-tiles
//      schedule (T3+T4): staging SPREAD across phases (2/2/0/4 gload_lds),
//      ONE counted vmcnt(4) per K-tile at P4 (never 0), quadrant order with
//      P4 read-free, XOR-swizzled LDS (conflicts=0), XCD swizzle, setprio,
//      sched_barrier(0) after lgkm waits (rule #18).  Fused LSTM epilogue.

#define NB   4096
#define KH   1024
#define KK   2048
#define ARR_ELEMS 4194304  // 4096*1024
#define NKT  32            // K tiles of 64

typedef __bf16 bf16x8 __attribute__((ext_vector_type(8)));
typedef float  f32x4  __attribute__((ext_vector_type(4)));

__device__ inline unsigned short f2bf(float f) {
    union { float f; unsigned int u; } v; v.f = f;
    unsigned int u = v.u;
    u += 0x7FFFu + ((u >> 16) & 1u);   // RNE
    return (unsigned short)(u >> 16);
}

__device__ inline float fsig(float v)  { return __builtin_amdgcn_rcpf(1.f + __expf(-v)); }
__device__ inline float ftanh(float v) { return 1.f - 2.f * __builtin_amdgcn_rcpf(1.f + __expf(2.f * v)); }

// ---------------------------------------------------------------- convert ---
__global__ void convert_kernel(const float* __restrict__ h, const float* __restrict__ x,
                               const float* __restrict__ Wh, const float* __restrict__ Wx,
                               unsigned short* __restrict__ A, unsigned short* __restrict__ W) {
    int idx = blockIdx.x * 256 + threadIdx.x;       // 0 .. 2M-1
    int arr = idx >> 19;
    int off = (idx & 0x7FFFF) << 3;
    const float* src = (arr == 0) ? h : (arr == 1) ? x : (arr == 2) ? Wh : Wx;
    float4 v0 = *(const float4*)(src + off);
    float4 v1 = *(const float4*)(src + off + 4);
    uint4 packed;
    packed.x = (unsigned int)f2bf(v0.x) | ((unsigned int)f2bf(v0.y) << 16);
    packed.y = (unsigned int)f2bf(v0.z) | ((unsigned int)f2bf(v0.w) << 16);
    packed.z = (unsigned int)f2bf(v1.x) | ((unsigned int)f2bf(v1.y) << 16);
    packed.w = (unsigned int)f2bf(v1.z) | ((unsigned int)f2bf(v1.w) << 16);

    int row = off >> 10;
    int col = off & 1023;
    unsigned short* dst;
    size_t dstOff;
    if (arr < 2) {                                  // A_cat: [h | x] per row
        dst = A;
        dstOff = (size_t)row * KK + (arr == 1 ? 1024 : 0) + col;
    } else {                                        // W_cat: permuted rows
        int g = row >> 10, j = row & 1023;
        int p = ((j >> 4) << 6) | (g << 4) | (j & 15);
        dst = W;
        dstOff = (size_t)p * KK + (arr == 3 ? 1024 : 0) + col;
    }
    *(uint4*)(dst + dstOff) = packed;
}

// ------------------------------------------------------------------- gemm ---
// 512 threads = 8 waves (2 M-halves x 4 N-quarters). Wave output 128x64.
// LDS: double-buffered K-tiles, [256 rows][64 k] bf16 per matrix per buffer,
// XOR swizzle phys_byte = row*128 + (kbyte ^ ((row&7)<<4)); staging keeps LDS
// linear (global_load_lds) with pre-swizzled per-lane GLOBAL source.
//
// Per K-tile T (buf = T&1), 4 phases; each phase ends in
// [barrier; lgkm(0); sched_barrier; setprio(1); 16 MFMA; setprio(0); barrier]:
//   P1: read a03(8),b01(4); stage A(T+1)h0 -> buf^1; lgkm(8);  q1=a03*b01
//   P2: read b23(4);        stage A(T+1)h1 -> buf^1;           q2=a03*b23
//   P3: read a47(8);                                           q3=a47*b23
//   P4: stage B(T+2)h0,h1 -> buf;  q4=a47*b01 (reg-only); vmcnt(4); barrier
//
// Hazard invariants:
//  - B(T) dead after P2 (every wave's b01/b23 reads drained by its own P2
//    lgkm(0); P2 trailing barrier) -> P4's B(T+2) stage into buf is safe.
//  - A-region of buf^1 dead since tile T-1 P3 -> P1/P2 A(T+1) stage safe.
//  - P4's vmcnt(4) drains A(T+1) (and older), leaves B(T+2) (newest 4) in
//    flight; trailing barrier publishes -> tile T+1's P1 reads are valid.
//  - vmcnt never drains to 0 in the loop.
__global__ __launch_bounds__(512, 2) void gemm_kernel(const unsigned short* __restrict__ A,
                            const unsigned short* __restrict__ W,
                            const float* __restrict__ bh,
                            const float* __restrict__ c,
                            float* __restrict__ out) {
    __shared__ __align__(16) unsigned short As[2 * 16384];   // 64 KiB
    __shared__ __align__(16) unsigned short Bs[2 * 16384];   // 64 KiB

    const int tid  = threadIdx.x;
    const int wave = tid >> 6;
    const int lane = tid & 63;

    // T1: 256 blocks, 8 XCDs -> contiguous 32-tile chunks per XCD
    const int bid   = (int)blockIdx.x;
    const int swz   = (bid & 7) * 32 + (bid >> 3);
    const int tileM = swz >> 4;        // 0..15
    const int tileN = swz & 15;        // 0..15

    const int wr  = wave >> 2;         // 0..1  M half
    const int wc  = wave & 3;          // 0..3  N quarter
    const int fr  = lane & 15;
    const int fk2 = (lane >> 4) << 4;  // fragment byte k-offset {0,16,32,48}

    // ---- staging: per-thread pre-swizzled global source pointers ----------
    // chunk i*512+tid covers LDS phys bytes [(i*512+tid)*16, +16); halves:
    // i in {0,1} = rows 0..127, i in {2,3} = rows 128..255.
    const unsigned short* pa[4];
    const unsigned short* pb[4];
    #pragma unroll
    for (int i = 0; i < 4; ++i) {
        const int P   = (i * 512 + tid) * 16;
        const int L   = P ^ (((P >> 7) & 7) << 4);
        const int row = L >> 7;
        const int kk  = (L & 127) >> 1;
        pa[i] = A + (size_t)(tileM * 256 + row) * KK + kk;
        pb[i] = W + (size_t)(tileN * 256 + row) * KK + kk;
    }

    // ---- compute-side swizzled LDS byte offsets ---------------------------
    const int swzm = (fr & 7) << 4;
    int offA[8], offB[4];
    #pragma unroll
    for (int i = 0; i < 8; ++i)
        offA[i] = (wr * 128 + i * 16 + fr) * 128 + (fk2 ^ swzm);
    #pragma unroll
    for (int j = 0; j < 4; ++j)
        offB[j] = (wc * 64 + j * 16 + fr) * 128 + (fk2 ^ swzm);
    // second K=32 panel: offset ^ 64

    f32x4 acc[8][4] = {};
    bf16x8 a03[4][2], a47[4][2], b01[2][2], b23[2][2];

#define STAGE_A(H, KT, BUF) do { \
    const size_t _ko = (size_t)(KT) * 64; \
    _Pragma("unroll") \
    for (int _i = 2*(H); _i < 2*(H)+2; ++_i) \
        __builtin_amdgcn_global_load_lds( \
            (const __attribute__((address_space(1))) void*)(pa[_i] + _ko), \
            (__attribute__((address_space(3))) void*)(As + (BUF) * 16384 + _i * 4096 + wave * 512), 16, 0, 0); \
} while (0)

#define STAGE_B(H, KT, BUF) do { \
    const size_t _ko = (size_t)(KT) * 64; \
    _Pragma("unroll") \
    for (int _i = 2*(H); _i < 2*(H)+2; ++_i) \
        __builtin_amdgcn_global_load_lds( \
            (const __attribute__((address_space(1))) void*)(pb[_i] + _ko), \
            (__attribute__((address_space(3))) void*)(Bs + (BUF) * 16384 + _i * 4096 + wave * 512), 16, 0, 0); \
} while (0)

#define READ_A(dst, base, AsB) do { \
    _Pragma("unroll") \
    for (int _i = 0; _i < 4; ++_i) { \
        dst[_i][0] = *(const bf16x8*)((AsB) + offA[(base) + _i]); \
        dst[_i][1] = *(const bf16x8*)((AsB) + (offA[(base) + _i] ^ 64)); \
    } \
} while (0)

#define READ_B(dst, base, BsB) do { \
    _Pragma("unroll") \
    for (int _j = 0; _j < 2; ++_j) { \
        dst[_j][0] = *(const bf16x8*)((BsB) + offB[(base) + _j]); \
        dst[_j][1] = *(const bf16x8*)((BsB) + (offB[(base) + _j] ^ 64)); \
    } \
} while (0)

#define MFMAQ(af, bf, IB, JB) do { \
    _Pragma("unroll") \
    for (int _i = 0; _i < 4; ++_i) \
        _Pragma("unroll") \
        for (int _j = 0; _j < 2; ++_j) \
            _Pragma("unroll") \
            for (int _s = 0; _s < 2; ++_s) \
                acc[(IB) + _i][(JB) + _j] = __builtin_amdgcn_mfma_f32_16x16x32_bf16( \
                    af[_i][_s], bf[_j][_s], acc[(IB) + _i][(JB) + _j], 0, 0, 0); \
} while (0)

#define PH_TAIL(MF) \
    __builtin_amdgcn_s_barrier(); \
    asm volatile("s_waitcnt lgkmcnt(0)" ::: "memory"); \
    __builtin_amdgcn_sched_barrier(0); \
    __builtin_amdgcn_s_setprio(1); \
    MF; \
    __builtin_amdgcn_s_setprio(0); \
    __builtin_amdgcn_s_barrier();

#define TILEBODY(T, BUF) do { \
    const char* AsB = (const char*)As + (BUF) * 32768; \
    const char* BsB = (const char*)Bs + (BUF) * 32768; \
    const int _t1 = ((T) + 1 <= NKT - 1) ? ((T) + 1) : (NKT - 1); \
    const int _t2 = ((T) + 2 <= NKT - 1) ? ((T) + 2) : (NKT - 1); \
    /* P1 */ \
    READ_A(a03, 0, AsB); \
    READ_B(b01, 0, BsB); \
    STAGE_A(0, _t1, (BUF) ^ 1); \
    asm volatile("s_waitcnt lgkmcnt(8)" ::: "memory"); \
    PH_TAIL(MFMAQ(a03, b01, 0, 0)) \
    /* P2 */ \
    READ_B(b23, 2, BsB); \
    STAGE_A(1, _t1, (BUF) ^ 1); \
    PH_TAIL(MFMAQ(a03, b23, 0, 2)) \
    /* P3 */ \
    READ_A(a47, 4, AsB); \
    PH_TAIL(MFMAQ(a47, b23, 4, 2)) \
    /* P4: B(T) died at P2 -> stage B(T+2) into this buf */ \
    STAGE_B(0, _t2, BUF); \
    STAGE_B(1, _t2, BUF); \
    __builtin_amdgcn_s_barrier(); \
    __builtin_amdgcn_s_setprio(1); \
    MFMAQ(a47, b01, 4, 0); \
    __builtin_amdgcn_s_setprio(0); \
    asm volatile("s_waitcnt vmcnt(4)" ::: "memory"); \
    __builtin_amdgcn_s_barrier(); \
} while (0)

    // prologue: A(0),B(0)->buf0, B(1)->buf1; vmcnt(4) keeps B(1) in flight
    STAGE_A(0, 0, 0); STAGE_A(1, 0, 0);
    STAGE_B(0, 0, 0); STAGE_B(1, 0, 0);
    STAGE_B(0, 1, 1); STAGE_B(1, 1, 1);
    asm volatile("s_waitcnt vmcnt(4)" ::: "memory");
    __builtin_amdgcn_s_barrier();

    for (int tt = 0; tt < NKT; tt += 2) {
        TILEBODY(tt, 0);
        TILEBODY(tt + 1, 1);
    }
#undef TILEBODY
#undef PH_TAIL
#undef MFMAQ
#undef READ_A
#undef READ_B
#undef STAGE_A
#undef STAGE_B

    // ---- fused LSTM gate epilogue (r1-verified 256^2 mapping) -------------
    // acc[i][g][r]: row = tileM*256 + wr*128 + i*16 + (lane>>4)*4 + r,
    // gate g, logical j = (tileN*4+wc)*16 + (lane&15)
    const int j = ((tileN * 4 + wc) << 4) | fr;
    const float bi  = bh[j];
    const float bff = bh[j + 1024];
    const float bg  = bh[j + 2048];
    const float bo  = bh[j + 3072];

    const int row0 = tileM * 256 + wr * 128 + (lane >> 4) * 4;

    float cv[8][4];
    #pragma unroll
    for (int i = 0; i < 8; ++i)
        #pragma unroll
        for (int r = 0; r < 4; ++r)
            cv[i][r] = c[(size_t)(row0 + i * 16 + r) * KH + j];

    #pragma unroll
    for (int i = 0; i < 8; ++i) {
        #pragma unroll
        for (int r = 0; r < 4; ++r) {
            const size_t idx = (size_t)(row0 + i * 16 + r) * KH + j;
            float iv = fsig(acc[i][0][r] + bi);
            float fv = fsig(acc[i][1][r] + bff);
            float gv = ftanh(acc[i][2][r] + bg);
            float ov = fsig(acc[i][3][r] + bo);
            float cn = fv * cv[i][r] + iv * gv;
            float hn = ov * ftanh(cn);
            out[idx] = hn;
            out[(size_t)ARR_ELEMS + idx] = cn;
        }
    }
}

// ----------------------------------------------------------------- launch ---
extern "C" void kernel_launch(void* const* d_in, const int* in_sizes, int n_in,
                              void* d_out, int out_size, void* d_ws, size_t ws_size,
                              hipStream_t stream) {
    const float* x  = (const float*)d_in[0];
    const float* h  = (const float*)d_in[1];
    const float* c  = (const float*)d_in[2];
    const float* Wh = (const float*)d_in[3];
    const float* bh = (const float*)d_in[4];
    const float* Wx = (const float*)d_in[5];
    float* out = (float*)d_out;

    unsigned short* ws   = (unsigned short*)d_ws;
    unsigned short* Acat = ws;
    unsigned short* Wcat = ws + 2 * (size_t)ARR_ELEMS;

    convert_kernel<<<8192, 256, 0, stream>>>(h, x, Wh, Wx, Acat, Wcat);
    gemm_kernel<<<256, 512, 0, stream>>>(Acat, Wcat, bh, c, out);
}